// Round 5
// baseline (487.804 us; speedup 1.0000x reference)
//
#include <hip/hip_runtime.h>

typedef __bf16 bf16x8 __attribute__((ext_vector_type(8)));
typedef __bf16 bf16x4 __attribute__((ext_vector_type(4)));
typedef float floatx4 __attribute__((ext_vector_type(4)));

#define GK 2048
#define S_LEN 2048
#define NH 16
#define DH 128

__device__ __forceinline__ void gl2lds16(const __bf16* g, __bf16* l) {
    __builtin_amdgcn_global_load_lds(
        (const __attribute__((address_space(1))) void*)g,
        (__attribute__((address_space(3))) void*)l, 16, 0, 0);
}

// ---------------------------------------------------------------------------
// fp32 -> bf16 bulk convert (one float4 -> bf16x4 per thread)
// ---------------------------------------------------------------------------
__global__ __launch_bounds__(256) void cvt_bf16(const float* __restrict__ in,
                                                __bf16* __restrict__ out, int n4) {
    int i = blockIdx.x * 256 + threadIdx.x;
    if (i < n4) {
        const float4 v = ((const float4*)in)[i];
        bf16x4 h;
        h[0] = (__bf16)v.x; h[1] = (__bf16)v.y; h[2] = (__bf16)v.z; h[3] = (__bf16)v.w;
        ((bf16x4*)out)[i] = h;
    }
}

// concat-convert wq|wk|wv (each 2048x2048 fp32) -> one bf16 [6144][2048]
__global__ __launch_bounds__(256) void cvt3_bf16(const float* __restrict__ a,
                                                 const float* __restrict__ b,
                                                 const float* __restrict__ c,
                                                 __bf16* __restrict__ out) {
    const int per = 2048 * 2048 / 4;
    int i = blockIdx.x * 256 + threadIdx.x;      // 0 .. 3*per-1
    const float* src = a; int j = i;
    if (i >= 2 * per)      { src = c; j = i - 2 * per; }
    else if (i >= per)     { src = b; j = i - per; }
    const float4 v = ((const float4*)src)[j];
    bf16x4 h;
    h[0] = (__bf16)v.x; h[1] = (__bf16)v.y; h[2] = (__bf16)v.z; h[3] = (__bf16)v.w;
    ((bf16x4*)out)[i] = h;
}

// ---------------------------------------------------------------------------
// Pure-bf16 K-loop: C[m][n] = sum_k A[m][k] * W[n][k], both staged via
// global_load_lds width-16. 128x128 tile, BK=32, 4 waves, 4x4 MFMA/wave.
// ---------------------------------------------------------------------------
__device__ __forceinline__ void gemm_body(const __bf16* __restrict__ A,
                                          const __bf16* __restrict__ W,
                                          int m0, int n0,
                                          __bf16 (*As)[32], __bf16 (*Bs)[32],
                                          floatx4 (*acc)[4]) {
    const int t = threadIdx.x, lane = t & 63, wave = t >> 6;
    const int fr = lane & 15, fq = lane >> 4;
    const int wr = (wave >> 1) * 64, wc = (wave & 1) * 64;

    const __bf16* Ap = A + (size_t)(m0 + wave * 32 + (lane >> 2)) * GK + (lane & 3) * 8;
    const __bf16* Wp = W + (size_t)(n0 + wave * 32 + (lane >> 2)) * GK + (lane & 3) * 8;
    __bf16* lA0 = &As[wave * 32][0];
    __bf16* lA1 = &As[wave * 32 + 16][0];
    __bf16* lB0 = &Bs[wave * 32][0];
    __bf16* lB1 = &Bs[wave * 32 + 16][0];

    for (int k0 = 0; k0 < GK; k0 += 32) {
        gl2lds16(Ap, lA0);
        gl2lds16(Ap + (size_t)16 * GK, lA1);
        gl2lds16(Wp, lB0);
        gl2lds16(Wp + (size_t)16 * GK, lB1);
        Ap += 32; Wp += 32;
        __syncthreads();   // drains vmcnt + orders LDS

        bf16x8 af[4], bfg[4];
        for (int i = 0; i < 4; i++) af[i]  = *(const bf16x8*)&As[wr + i * 16 + fr][fq * 8];
        for (int j = 0; j < 4; j++) bfg[j] = *(const bf16x8*)&Bs[wc + j * 16 + fr][fq * 8];
        for (int i = 0; i < 4; i++)
            for (int j = 0; j < 4; j++)
                acc[i][j] = __builtin_amdgcn_mfma_f32_16x16x32_bf16(af[i], bfg[j], acc[i][j], 0, 0, 0);
        __syncthreads();
    }
}

// Fused QKV projection: A (4096x2048 bf16) x Wqkv (6144x2048 bf16).
// n<2048 -> qb, n<4096 -> kb (row-major [b*S][2048]); n>=4096 -> vbT
// ([b][h*128+d][s], transposed for flash staging).
__global__ __launch_bounds__(256) void gemm_qkv(const __bf16* __restrict__ A,
                                                const __bf16* __restrict__ W,
                                                __bf16* __restrict__ qb,
                                                __bf16* __restrict__ kb,
                                                __bf16* __restrict__ vbT) {
    __shared__ __align__(16) __bf16 As[128][32];
    __shared__ __align__(16) __bf16 Bs[128][32];
    const int m0 = blockIdx.y * 128, n0 = blockIdx.x * 128;
    floatx4 acc[4][4] = {};
    gemm_body(A, W, m0, n0, As, Bs, acc);

    const int lane = threadIdx.x & 63, wave = threadIdx.x >> 6;
    const int fr = lane & 15, fq = lane >> 4;
    const int wr = (wave >> 1) * 64, wc = (wave & 1) * 64;
    const int which = n0 >> 11;          // 0=q 1=k 2=v (block-uniform)
    const int nc0 = n0 & 2047;

    for (int i = 0; i < 4; i++)
        for (int j = 0; j < 4; j++) {
            const int row = m0 + wr + i * 16 + fq * 4;
            const int col = nc0 + wc + j * 16 + fr;
            if (which == 2) {
                // vbT[b][col][s]; b = row>>11, s = row&2047 (row%4==0 -> 8B aligned)
                __bf16* Cp = vbT + (((size_t)(row & ~2047)) << 11) +
                             (size_t)col * 2048 + (row & 2047);
                bf16x4 hv;
                for (int r = 0; r < 4; r++) hv[r] = (__bf16)acc[i][j][r];
                *(bf16x4*)Cp = hv;
            } else {
                __bf16* dst = which ? kb : qb;
                for (int r = 0; r < 4; r++)
                    dst[(size_t)(row + r) * 2048 + col] = (__bf16)acc[i][j][r];
            }
        }
}

// Out-projection: A (4096x2048 bf16) x Wo (2048x2048 bf16) -> fp32 out
__global__ __launch_bounds__(256) void gemm_out(const __bf16* __restrict__ A,
                                                const __bf16* __restrict__ W,
                                                float* __restrict__ C) {
    __shared__ __align__(16) __bf16 As[128][32];
    __shared__ __align__(16) __bf16 Bs[128][32];
    const int m0 = blockIdx.y * 128, n0 = blockIdx.x * 128;
    floatx4 acc[4][4] = {};
    gemm_body(A, W, m0, n0, As, Bs, acc);

    const int lane = threadIdx.x & 63, wave = threadIdx.x >> 6;
    const int fr = lane & 15, fq = lane >> 4;
    const int wr = (wave >> 1) * 64, wc = (wave & 1) * 64;
    for (int i = 0; i < 4; i++)
        for (int j = 0; j < 4; j++) {
            const int row = m0 + wr + i * 16 + fq * 4;
            const int col = n0 + wc + j * 16 + fr;
            for (int r = 0; r < 4; r++)
                C[(size_t)(row + r) * 2048 + col] = acc[i][j][r];
        }
}

// ---------------------------------------------------------------------------
// Fused RMSNorm + RoPE, vectorized: 16 lanes per (b,s,h) row, bf16x8 per lane.
// RoPE pair (d, d+64) exchanged via shfl_xor(8). fp32 math throughout.
// ---------------------------------------------------------------------------
__global__ __launch_bounds__(256) void rmsrope(__bf16* __restrict__ qb,
                                               __bf16* __restrict__ kb,
                                               const float* __restrict__ rope,
                                               const float* __restrict__ qw,
                                               const float* __restrict__ kw) {
    const int t = threadIdx.x;
    const int row = blockIdx.x * 16 + (t >> 4);            // (b*S + s)*H + h
    const int c = t & 15;                                  // 8-elem chunk index
    __bf16* p = (blockIdx.y ? kb : qb) + (size_t)row * DH + c * 8;
    const float* w = (blockIdx.y ? kw : qw) + c * 8;
    const int s = (row >> 4) & (S_LEN - 1);

    const bf16x8 v = *(const bf16x8*)p;
    float n[8];
    float ss = 0.f;
    for (int i = 0; i < 8; i++) { n[i] = (float)v[i]; ss += n[i] * n[i]; }
    ss += __shfl_xor(ss, 1, 64);
    ss += __shfl_xor(ss, 2, 64);
    ss += __shfl_xor(ss, 4, 64);
    ss += __shfl_xor(ss, 8, 64);
    const float inv = rsqrtf(ss * (1.0f / 128.0f) + 1e-6f);
    const float4 w0 = *(const float4*)w, w1 = *(const float4*)(w + 4);
    n[0] *= inv * w0.x; n[1] *= inv * w0.y; n[2] *= inv * w0.z; n[3] *= inv * w0.w;
    n[4] *= inv * w1.x; n[5] *= inv * w1.y; n[6] *= inv * w1.z; n[7] *= inv * w1.w;

    float pn[8];
    for (int i = 0; i < 8; i++) pn[i] = __shfl_xor(n[i], 8, 64);

    const float4* f = (const float4*)(rope + (size_t)s * 256 + (c & 7) * 32);
    bf16x8 o;
    if (c < 8) {
        for (int i = 0; i < 8; i++) o[i] = (__bf16)(f[i].x * n[i] + f[i].y * pn[i]);
    } else {
        for (int i = 0; i < 8; i++) o[i] = (__bf16)(f[i].z * pn[i] + f[i].w * n[i]);
    }
    *(bf16x8*)p = o;
}

// ---------------------------------------------------------------------------
// Flash attention: fixed-max softmax (p = exp2(s*sc*log2e - M2)), l via MFMA
// ones-column (Vt row 128). Q-tile 64 (wave = 16 q-rows), KV tile 32.
// 1-D grid 1024, XCD-swizzled so each XCD sees only 4 (b,h) heads.
// V staged via global_load_lds into unpadded Vt[144][32].
// ---------------------------------------------------------------------------
__global__ __launch_bounds__(256) void flash(const __bf16* __restrict__ Q,
                                             const __bf16* __restrict__ K,
                                             const __bf16* __restrict__ Vt_g,
                                             __bf16* __restrict__ O) {
    __shared__ __align__(16) __bf16 Ks[32][136];    // [kv][d], pad 8
    __shared__ __align__(16) __bf16 Vt[144][32];    // [d][kv], rows 128+ = ones/zeros
    __shared__ __align__(16) __bf16 Ps[4][16][40];  // per-wave P [qr][kv]

    const int t = threadIdx.x, lane = t & 63, wave = t >> 6;
    const int fr = lane & 15, fq = lane >> 4;
    const int id = blockIdx.x;                       // 0..1023
    const int bh = (id & 7) + 8 * (id >> 8);         // XCD swizzle: id%8 fixes head-group
    const int qidx = (id >> 3) & 31;
    const int b = bh >> 4, h = bh & 15;
    const size_t baseQ = (size_t)b * S_LEN * 2048 + h * 128;
    const size_t baseV = (size_t)b * 2048 * 2048 + (size_t)h * 128 * 2048;
    const int q0 = qidx * 64 + wave * 16;
    const float sc2 = 0.08838834764831845f * 1.4426950408889634f;  // (1/sqrt(128))*log2e
    const float M2 = 12.0f * 1.4426950408889634f;

    // ones/zero rows for the l-column (rows 128..143; DMA never touches them)
    for (int idx = t; idx < 16 * 32; idx += 256)
        Vt[128 + (idx >> 5)][idx & 31] = ((idx >> 5) == 0) ? (__bf16)1.0f : (__bf16)0.0f;

    // Q fragments (A layout), 4 k-chunks of 32
    bf16x8 qf[4];
    {
        const __bf16* qp = Q + baseQ + (size_t)(q0 + fr) * 2048 + fq * 8;
        for (int c = 0; c < 4; c++) qf[c] = *(const bf16x8*)(qp + c * 32);
    }

    floatx4 oa[9] = {};   // 8 d-tiles + l-tile

    const __bf16* Kp = K + baseQ + (size_t)(t >> 3) * 2048 + (t & 7) * 16;
    // V DMA: wave covers d-rows [wave*32, wave*32+32), 16 rows per instruction
    const __bf16* Vp = Vt_g + baseV + (size_t)(wave * 32 + (lane >> 2)) * 2048 + (lane & 3) * 8;
    __bf16* lV0 = &Vt[wave * 32][0];
    __bf16* lV1 = &Vt[wave * 32 + 16][0];

    for (int kv0 = 0; kv0 < S_LEN; kv0 += 32) {
        *(uint4*)&Ks[t >> 3][(t & 7) * 16]     = *(const uint4*)(Kp);
        *(uint4*)&Ks[t >> 3][(t & 7) * 16 + 8] = *(const uint4*)(Kp + 8);
        gl2lds16(Vp, lV0);
        gl2lds16(Vp + (size_t)16 * 2048, lV1);
        Kp += (size_t)32 * 2048;
        Vp += 32;
        __syncthreads();   // drains vmcnt (V DMA) + LDS writes

        // S = Q K^T: 2 kv-subtiles
        floatx4 s0 = {}, s1 = {};
        for (int c = 0; c < 4; c++) {
            const bf16x8 kf0 = *(const bf16x8*)&Ks[fr][c * 32 + fq * 8];
            const bf16x8 kf1 = *(const bf16x8*)&Ks[fr + 16][c * 32 + fq * 8];
            s0 = __builtin_amdgcn_mfma_f32_16x16x32_bf16(qf[c], kf0, s0, 0, 0, 0);
            s1 = __builtin_amdgcn_mfma_f32_16x16x32_bf16(qf[c], kf1, s1, 0, 0, 0);
        }

        // P = exp2(s*sc2 - M2), straight to LDS (C-layout row = fq*4+r, col = fr)
        for (int r = 0; r < 4; r++) {
            const int row = fq * 4 + r;
            Ps[wave][row][fr]      = (__bf16)exp2f(fmaf(sc2, s0[r], -M2));
            Ps[wave][row][fr + 16] = (__bf16)exp2f(fmaf(sc2, s1[r], -M2));
        }

        // O += P V (l in tile 8); per-wave Ps: no barrier needed
        const bf16x8 pf = *(const bf16x8*)&Ps[wave][fr][fq * 8];
        for (int nb = 0; nb < 9; nb++) {
            const bf16x8 vf = *(const bf16x8*)&Vt[nb * 16 + fr][fq * 8];
            oa[nb] = __builtin_amdgcn_mfma_f32_16x16x32_bf16(pf, vf, oa[nb], 0, 0, 0);
        }
        __syncthreads();   // all tile reads done before next staging
    }

    for (int r = 0; r < 4; r++) {
        float l = oa[8][r];              // ones-column lives at fr==0
        l = __shfl(l, fq * 16);          // broadcast within the fq row-group
        const float inv = 1.0f / l;
        __bf16* op = O + baseQ + (size_t)(q0 + fq * 4 + r) * 2048;
        for (int nb = 0; nb < 8; nb++)
            op[nb * 16 + fr] = (__bf16)(oa[nb][r] * inv);
    }
}

// ---------------------------------------------------------------------------
extern "C" void kernel_launch(void* const* d_in, const int* in_sizes, int n_in,
                              void* d_out, int out_size, void* d_ws, size_t ws_size,
                              hipStream_t stream) {
    const float* x    = (const float*)d_in[0];
    const float* rope = (const float*)d_in[1];
    const float* wq   = (const float*)d_in[2];
    const float* wk   = (const float*)d_in[3];
    const float* wv   = (const float*)d_in[4];
    const float* wo   = (const float*)d_in[5];
    const float* qnw  = (const float*)d_in[6];
    const float* knw  = (const float*)d_in[7];
    float* out = (float*)d_out;

    const size_t NTOK = 2 * 2048;
    const size_t ELEMS = NTOK * 2048;            // 8388608
    __bf16* xb  = (__bf16*)d_ws;                 // 16 MB; reused as ob after flash
    __bf16* qb  = xb + ELEMS;                    // 16 MB; reused for wo_bf after flash
    __bf16* kb  = qb + ELEMS;
    __bf16* vbT = kb + ELEMS;
    __bf16* ob  = xb;
    // d_out (32 MB fp32) doubles as scratch for the concatenated bf16 QKV
    // weights (25.2 MB) — fully consumed by gemm_qkv before gemm_out writes it.
    __bf16* wqkv = (__bf16*)d_out;
    __bf16* wob  = qb;                           // wo bf16 (8 MB), written after flash

    cvt_bf16<<<(int)(ELEMS / 4) / 256, 256, 0, stream>>>(x, xb, (int)(ELEMS / 4));
    cvt3_bf16<<<3 * (2048 * 2048 / 4) / 256, 256, 0, stream>>>(wq, wk, wv, wqkv);
    gemm_qkv<<<dim3(6144 / 128, (unsigned)(NTOK / 128)), 256, 0, stream>>>(xb, wqkv, qb, kb, vbT);
    rmsrope<<<dim3((unsigned)(NTOK * NH / 16), 2), 256, 0, stream>>>(qb, kb, rope, qnw, knw);
    flash<<<dim3(1024), 256, 0, stream>>>(qb, kb, vbT, ob);
    cvt_bf16<<<(int)(2048 * 2048 / 4) / 256, 256, 0, stream>>>(wo, wob, 2048 * 2048 / 4);
    gemm_out<<<dim3(2048 / 128, (unsigned)(NTOK / 128)), 256, 0, stream>>>(ob, wob, out);
}